// Round 10
// baseline (608.243 us; speedup 1.0000x reference)
//
#include <hip/hip_runtime.h>
#include <hip/hip_cooperative_groups.h>
#include <hip/hip_bf16.h>
#include <math.h>

namespace cg = cooperative_groups;

#define N_NODES 50000
#define E_RAW   800000
#define E_TOT   850000
#define NEG_SLOPE 0.2f
#define CAP 64   // ELL slots per node; deg = Poisson(16)+1, P(>64) ~ 1e-13

#define GB1 782    // gemm1 vblocks (50000/64 rounded up)
#define EB1 3321   // scatter vblocks
#define AB2 3125   // aggr1+gemm2 vblocks (16 dsts each)
#define RB3 12500  // aggr2 vblocks (4 dsts each)

typedef __attribute__((ext_vector_type(8))) short short8;
typedef __attribute__((ext_vector_type(4))) float f32x4;

__device__ __forceinline__ short f2bf(float f) {
    __hip_bfloat16 h = __float2bfloat16(f);
    return *reinterpret_cast<short*>(&h);
}
__device__ __forceinline__ unsigned int f2bfu(float f) {
    __hip_bfloat16 h = __float2bfloat16(f);
    return (unsigned int)*reinterpret_cast<unsigned short*>(&h);
}
__device__ __forceinline__ float bflo(unsigned int u) {
    return __uint_as_float(u << 16);
}
__device__ __forceinline__ float bfhi(unsigned int u) {
    return __uint_as_float(u & 0xffff0000u);
}

// ============ W -> B-fragment-order bf16 swizzle ============
template<int K, int N>
__device__ __forceinline__ void wf_body(
        int blk, const float* __restrict__ W, short* __restrict__ Wf) {
    constexpr int NT = N / 16;
    const int idx = blk * 256 + threadIdx.x;
    if (idx >= K * N) return;
    const int j  = idx & 7;
    const int n  = (idx >> 3) & 15;
    const int q  = (idx >> 7) & 3;
    const int t  = (idx >> 9) % NT;
    const int kc = idx / (512 * NT);
    const int k   = kc * 32 + q * 8 + j;
    const int col = t * 16 + n;
    Wf[idx] = f2bf(W[(size_t)k * N + col]);
}

// ============ phase 0: zero cnt + both swizzles (196 vblocks) ============
__device__ __forceinline__ void phase0_body(
        int vb, int* __restrict__ cnt,
        const float* __restrict__ W1, short* __restrict__ Wf1,
        const float* __restrict__ W2, short* __restrict__ Wf2) {
    const int idx = vb * 256 + threadIdx.x;
    if (idx < N_NODES) cnt[idx] = 0;
    if (vb < 128)      wf_body<256, 128>(vb, W1, Wf1);
    else if (vb < 160) wf_body<128, 64>(vb - 128, W2, Wf2);
}

// ============ MFMA GEMM1 + fused attention scores ============
__device__ __forceinline__ void gemm1_body(
        const int blk,
        const float* __restrict__ xf, const short* __restrict__ Wf,
        const float* __restrict__ att_src, const float* __restrict__ att_dst,
        short* __restrict__ h_bf,
        float* __restrict__ a_src, float* __restrict__ a_dst) {
    constexpr int K = 256, N = 128, NT = 8, KC = 8;
    const int lane = threadIdx.x & 63;
    const int wv   = threadIdx.x >> 6;
    const int mrow = lane & 15;
    const int q    = lane >> 4;

    const int row0 = blk * 64 + wv * 16;
    const int rowA = row0 + mrow;
    const int rowAc = rowA < N_NODES ? rowA : 0;

    f32x4 acc[NT];
    #pragma unroll
    for (int t = 0; t < NT; ++t) acc[t] = f32x4{0.f, 0.f, 0.f, 0.f};

    #pragma unroll
    for (int kc = 0; kc < KC; ++kc) {
        short8 a;
        const float4 f0 = *(const float4*)&xf[(size_t)rowAc * K + kc * 32 + q * 8];
        const float4 f1 = *(const float4*)&xf[(size_t)rowAc * K + kc * 32 + q * 8 + 4];
        a[0] = f2bf(f0.x); a[1] = f2bf(f0.y); a[2] = f2bf(f0.z); a[3] = f2bf(f0.w);
        a[4] = f2bf(f1.x); a[5] = f2bf(f1.y); a[6] = f2bf(f1.z); a[7] = f2bf(f1.w);
        #pragma unroll
        for (int t = 0; t < NT; ++t) {
            const short8 b = *(const short8*)&Wf[((size_t)(kc * NT + t) * 64 + lane) * 8];
            acc[t] = __builtin_amdgcn_mfma_f32_16x16x32_bf16(a, b, acc[t], 0, 0, 0);
        }
    }

    // D layout: col = mrow, row = q*4 + r
    #pragma unroll
    for (int r = 0; r < 4; ++r) {
        const int rowD = row0 + q * 4 + r;
        float ps = 0.0f, pd = 0.0f;
        #pragma unroll
        for (int t = 0; t < NT; ++t) {
            const int col = t * 16 + mrow;
            ps = fmaf(acc[t][r], att_src[col], ps);
            pd = fmaf(acc[t][r], att_dst[col], pd);
        }
        #pragma unroll
        for (int off = 8; off > 0; off >>= 1) {
            ps += __shfl_xor(ps, off);
            pd += __shfl_xor(pd, off);
        }
        if (rowD < N_NODES) {
            if (mrow == 0) { a_src[rowD] = ps; a_dst[rowD] = pd; }
            #pragma unroll
            for (int t = 0; t < NT; ++t)
                h_bf[(size_t)rowD * N + t * 16 + mrow] = f2bf(acc[t][r]);
        }
    }
}

__device__ __forceinline__ void scatter_body(
        int vb, const int* __restrict__ ei,
        int* __restrict__ cnt, int* __restrict__ srcs) {
    const int i = vb * 256 + threadIdx.x;
    if (i >= E_TOT) return;
    int s, d;
    if (i < E_RAW) { s = ei[i]; d = ei[E_RAW + i]; }
    else           { s = d = i - E_RAW; }
    const int c = atomicAdd(&cnt[d], 1);
    if (c < CAP) srcs[(d << 6) + c] = s;
}

// ===== per-dst softmax-weighted aggregation of one dst row into acc[8] =====
__device__ __forceinline__ void aggr1_row(
        int d, const int* __restrict__ cnt, const int* __restrict__ srcs,
        const float* __restrict__ a_src1, const float* __restrict__ a_dst1,
        const unsigned short* __restrict__ h1, int lane, float* acc) {
    const int beg = d << 6;
    int deg = cnt[d];
    deg = deg < CAP ? deg : CAP;
    const float ad = a_dst1[d];
    const int sreg = srcs[beg + (lane < deg ? lane : 0)];
    float e;
    if (lane < deg) {
        float t = a_src1[sreg] + ad;
        e = t > 0.0f ? t : NEG_SLOPE * t;
    } else {
        e = -1e30f;
    }
    float m = e;
    #pragma unroll
    for (int off = 32; off > 0; off >>= 1) m = fmaxf(m, __shfl_xor(m, off));
    const float anum = __expf(e - m);
    float ss = anum;
    #pragma unroll
    for (int off = 32; off > 0; off >>= 1) ss += __shfl_xor(ss, off);
    const float areg = anum / ss;

    const int g   = lane >> 4;
    const int sub = lane & 15;
    #pragma unroll
    for (int c = 0; c < 8; ++c) acc[c] = 0.0f;

    int ec = (g < deg) ? g : 0;
    int s = __shfl(sreg, ec);
    float alpha = __shfl(areg, ec);
    if (g >= deg) alpha = 0.0f;
    uint4 hv = *(const uint4*)(h1 + (size_t)s * 128 + sub * 8);

    for (int j = 0; j < deg; j += 4) {
        const int eidxn = j + 4 + g;
        const int ecn = eidxn < deg ? eidxn : 0;
        const int sn = __shfl(sreg, ecn);
        float alphan = __shfl(areg, ecn);
        if (eidxn >= deg) alphan = 0.0f;
        const uint4 hvn = *(const uint4*)(h1 + (size_t)sn * 128 + sub * 8);

        acc[0] = fmaf(alpha, bflo(hv.x), acc[0]);
        acc[1] = fmaf(alpha, bfhi(hv.x), acc[1]);
        acc[2] = fmaf(alpha, bflo(hv.y), acc[2]);
        acc[3] = fmaf(alpha, bfhi(hv.y), acc[3]);
        acc[4] = fmaf(alpha, bflo(hv.z), acc[4]);
        acc[5] = fmaf(alpha, bfhi(hv.z), acc[5]);
        acc[6] = fmaf(alpha, bflo(hv.w), acc[6]);
        acc[7] = fmaf(alpha, bfhi(hv.w), acc[7]);
        hv = hvn; alpha = alphan;
    }
    #pragma unroll
    for (int c = 0; c < 8; ++c) {
        acc[c] += __shfl_xor(acc[c], 16);
        acc[c] += __shfl_xor(acc[c], 32);
    }
}

// ===== phase 2: aggr1 (4 waves x 4 dsts -> 16-row LDS tile) + gemm2 + att2 =====
__device__ __forceinline__ void aggr1_gemm2_body(
        int vb, const int* __restrict__ cnt, const int* __restrict__ srcs,
        const float* __restrict__ a_src1, const float* __restrict__ a_dst1,
        const unsigned short* __restrict__ h1, const float* __restrict__ b1,
        const short* __restrict__ Wf2,
        const float* __restrict__ att_src2, const float* __restrict__ att_dst2,
        short* __restrict__ h2,
        float* __restrict__ a_src2, float* __restrict__ a_dst2,
        short (*T)[136], float (*psum)[16], float (*pdum)[16]) {
    const int lane = threadIdx.x & 63;
    const int wv   = threadIdx.x >> 6;       // 0..3
    const int sub  = lane & 15;
    const int d0   = vb * 16;

    for (int i = 0; i < 4; ++i) {
        const int d = d0 + wv * 4 + i;       // < 50000 (3125*16 exact)
        float acc[8];
        aggr1_row(d, cnt, srcs, a_src1, a_dst1, h1, lane, acc);
        // bias + relu -> bf16 -> LDS tile row
        const float4 b0 = *(const float4*)&b1[sub * 8];
        const float4 b1v = *(const float4*)&b1[sub * 8 + 4];
        float v[8];
        v[0] = fmaxf(acc[0] + b0.x, 0.0f);  v[1] = fmaxf(acc[1] + b0.y, 0.0f);
        v[2] = fmaxf(acc[2] + b0.z, 0.0f);  v[3] = fmaxf(acc[3] + b0.w, 0.0f);
        v[4] = fmaxf(acc[4] + b1v.x, 0.0f); v[5] = fmaxf(acc[5] + b1v.y, 0.0f);
        v[6] = fmaxf(acc[6] + b1v.z, 0.0f); v[7] = fmaxf(acc[7] + b1v.w, 0.0f);
        if (lane < 16) {
            uint4 p;
            p.x = f2bfu(v[0]) | (f2bfu(v[1]) << 16);
            p.y = f2bfu(v[2]) | (f2bfu(v[3]) << 16);
            p.z = f2bfu(v[4]) | (f2bfu(v[5]) << 16);
            p.w = f2bfu(v[6]) | (f2bfu(v[7]) << 16);
            *(uint4*)&T[wv * 4 + i][sub * 8] = p;
        }
    }
    __syncthreads();

    // gemm2: wave wv owns 16-col tile t = wv
    {
        const int t = wv;
        const int mrow = lane & 15;
        const int q    = lane >> 4;
        f32x4 gacc = f32x4{0.f, 0.f, 0.f, 0.f};
        #pragma unroll
        for (int kc = 0; kc < 4; ++kc) {
            const short8 a = *(const short8*)&T[mrow][kc * 32 + q * 8];
            const short8 b = *(const short8*)&Wf2[((kc * 4 + t) * 64 + lane) * 8];
            gacc = __builtin_amdgcn_mfma_f32_16x16x32_bf16(a, b, gacc, 0, 0, 0);
        }
        #pragma unroll
        for (int r = 0; r < 4; ++r) {
            const int rowL = q * 4 + r;
            const int col  = t * 16 + mrow;
            float ps = gacc[r] * att_src2[col];
            float pd = gacc[r] * att_dst2[col];
            #pragma unroll
            for (int off = 8; off > 0; off >>= 1) {
                ps += __shfl_xor(ps, off);
                pd += __shfl_xor(pd, off);
            }
            if (mrow == 0) { psum[t][rowL] = ps; pdum[t][rowL] = pd; }
            h2[(size_t)(d0 + rowL) * 64 + col] = f2bf(gacc[r]);
        }
    }
    __syncthreads();
    if (threadIdx.x < 16) {
        const int r = threadIdx.x;
        a_src2[d0 + r] = psum[0][r] + psum[1][r] + psum[2][r] + psum[3][r];
        a_dst2[d0 + r] = pdum[0][r] + pdum[1][r] + pdum[2][r] + pdum[3][r];
    }
    __syncthreads();   // protect T/psum reuse across vblock iterations
}

// ===== phase 3: layer-2 aggregation + log-softmax (one wave per dst) =====
__device__ __forceinline__ void aggr2_body(
        int vb, const int* __restrict__ cnt, const int* __restrict__ srcs,
        const float* __restrict__ a_src, const float* __restrict__ a_dst,
        const unsigned short* __restrict__ h_bf, const float* __restrict__ bias,
        float* __restrict__ outf) {
    const int lane = threadIdx.x & 63;
    const int wave = threadIdx.x >> 6;
    const int d = vb * 4 + wave;             // < 50000 (12500*4 exact)
    const int beg = d << 6;
    int deg = cnt[d];
    deg = deg < CAP ? deg : CAP;
    const float ad = a_dst[d];

    const int sreg = srcs[beg + (lane < deg ? lane : 0)];
    float e;
    if (lane < deg) {
        float t = a_src[sreg] + ad;
        e = t > 0.0f ? t : NEG_SLOPE * t;
    } else {
        e = -1e30f;
    }
    float m = e;
    #pragma unroll
    for (int off = 32; off > 0; off >>= 1) m = fmaxf(m, __shfl_xor(m, off));
    const float anum = __expf(e - m);
    float ss = anum;
    #pragma unroll
    for (int off = 32; off > 0; off >>= 1) ss += __shfl_xor(ss, off);
    const float areg = anum / ss;

    const int g   = lane >> 4;
    const int sub = lane & 15;
    float acc[4];
    #pragma unroll
    for (int c = 0; c < 4; ++c) acc[c] = 0.0f;

    int ec = (g < deg) ? g : 0;
    int s = __shfl(sreg, ec);
    float alpha = __shfl(areg, ec);
    if (g >= deg) alpha = 0.0f;
    uint2 hv = *(const uint2*)(h_bf + (size_t)s * 64 + sub * 4);

    for (int j = 0; j < deg; j += 4) {
        const int eidxn = j + 4 + g;
        const int ecn = eidxn < deg ? eidxn : 0;
        const int sn = __shfl(sreg, ecn);
        float alphan = __shfl(areg, ecn);
        if (eidxn >= deg) alphan = 0.0f;
        const uint2 hvn = *(const uint2*)(h_bf + (size_t)sn * 64 + sub * 4);

        acc[0] = fmaf(alpha, bflo(hv.x), acc[0]);
        acc[1] = fmaf(alpha, bfhi(hv.x), acc[1]);
        acc[2] = fmaf(alpha, bflo(hv.y), acc[2]);
        acc[3] = fmaf(alpha, bfhi(hv.y), acc[3]);
        hv = hvn; alpha = alphan;
    }
    #pragma unroll
    for (int c = 0; c < 4; ++c) {
        acc[c] += __shfl_xor(acc[c], 16);
        acc[c] += __shfl_xor(acc[c], 32);
    }

    float v[4];
    #pragma unroll
    for (int c = 0; c < 4; ++c) v[c] = acc[c] + bias[sub * 4 + c];
    float mm = fmaxf(fmaxf(v[0], v[1]), fmaxf(v[2], v[3]));
    #pragma unroll
    for (int off = 1; off < 16; off <<= 1) mm = fmaxf(mm, __shfl_xor(mm, off));
    float es = __expf(v[0] - mm) + __expf(v[1] - mm)
             + __expf(v[2] - mm) + __expf(v[3] - mm);
    #pragma unroll
    for (int off = 1; off < 16; off <<= 1) es += __shfl_xor(es, off);
    const float ls = logf(es);
    if (lane < 16) {
        float4 o;
        o.x = v[0] - mm - ls; o.y = v[1] - mm - ls;
        o.z = v[2] - mm - ls; o.w = v[3] - mm - ls;
        *(float4*)&outf[(size_t)d * 64 + sub * 4] = o;
    }
}

// ================= the cooperative mega-kernel =================
__global__ __launch_bounds__(256) void gat_mega_kernel(
        const float* x, const int* ei,
        const float* W1, const float* att_src1, const float* att_dst1, const float* b1,
        const float* W2, const float* att_src2, const float* att_dst2, const float* b2,
        float* out,
        int* cnt, int* srcs, short* hbf1, short* hbf2, short* Wf1, short* Wf2,
        float* a_src1, float* a_dst1, float* a_src2, float* a_dst2) {
    __shared__ __align__(16) short T[16][136];
    __shared__ float psum[4][16], pdum[4][16];
    cg::grid_group grid = cg::this_grid();
    const int nb = gridDim.x, b = blockIdx.x;

    // phase 0: zero cnt + weight swizzles
    for (int vb = b; vb < 196; vb += nb)
        phase0_body(vb, cnt, W1, Wf1, W2, Wf2);
    grid.sync();

    // phase 1: gemm1 + ELL scatter
    for (int vb = b; vb < GB1 + EB1; vb += nb) {
        if (vb < GB1)
            gemm1_body(vb, x, Wf1, att_src1, att_dst1, hbf1, a_src1, a_dst1);
        else
            scatter_body(vb - GB1, ei, cnt, srcs);
    }
    grid.sync();

    // phase 2: aggr1 + gemm2 + att2
    for (int vb = b; vb < AB2; vb += nb)
        aggr1_gemm2_body(vb, cnt, srcs, a_src1, a_dst1,
                         (const unsigned short*)hbf1, b1, Wf2,
                         att_src2, att_dst2, hbf2, a_src2, a_dst2,
                         T, psum, pdum);
    grid.sync();

    // phase 3: aggr2 + log-softmax
    for (int vb = b; vb < RB3; vb += nb)
        aggr2_body(vb, cnt, srcs, a_src2, a_dst2,
                   (const unsigned short*)hbf2, b2, out);
}

// ================= fallback kernels (4 regular launches) =================
__global__ __launch_bounds__(256) void gat_init_kernel(
        int* cnt, const float* W1, short* Wf1, const float* W2, short* Wf2) {
    phase0_body(blockIdx.x, cnt, W1, Wf1, W2, Wf2);
}

__global__ __launch_bounds__(256) void gat_fat1_kernel(
        const float* xf, const short* Wf,
        const float* att_src, const float* att_dst,
        short* h_bf, float* a_src, float* a_dst,
        const int* ei, int* cnt, int* srcs) {
    if ((int)blockIdx.x < GB1)
        gemm1_body(blockIdx.x, xf, Wf, att_src, att_dst, h_bf, a_src, a_dst);
    else
        scatter_body(blockIdx.x - GB1, ei, cnt, srcs);
}

__global__ __launch_bounds__(256) void gat_aggr1_gemm2_kernel(
        const int* cnt, const int* srcs,
        const float* a_src1, const float* a_dst1,
        const unsigned short* h1, const float* b1, const short* Wf2,
        const float* att_src2, const float* att_dst2,
        short* h2, float* a_src2, float* a_dst2) {
    __shared__ __align__(16) short T[16][136];
    __shared__ float psum[4][16], pdum[4][16];
    aggr1_gemm2_body(blockIdx.x, cnt, srcs, a_src1, a_dst1, h1, b1, Wf2,
                     att_src2, att_dst2, h2, a_src2, a_dst2, T, psum, pdum);
}

__global__ __launch_bounds__(256) void gat_aggr2_kernel(
        const int* cnt, const int* srcs,
        const float* a_src, const float* a_dst,
        const unsigned short* h_bf, const float* bias, float* outf) {
    aggr2_body(blockIdx.x, cnt, srcs, a_src, a_dst, h_bf, bias, outf);
}

extern "C" void kernel_launch(void* const* d_in, const int* in_sizes, int n_in,
                              void* d_out, int out_size, void* d_ws, size_t ws_size,
                              hipStream_t stream) {
    const float* x        = (const float*)d_in[0];
    const int*   ei       = (const int*)  d_in[1];
    const float* W1       = (const float*)d_in[2];
    const float* att_src1 = (const float*)d_in[3];
    const float* att_dst1 = (const float*)d_in[4];
    const float* b1       = (const float*)d_in[5];
    const float* W2       = (const float*)d_in[6];
    const float* att_src2 = (const float*)d_in[7];
    const float* att_dst2 = (const float*)d_in[8];
    const float* b2       = (const float*)d_in[9];
    float* out = (float*)d_out;
    float* ws  = (float*)d_ws;

    // workspace layout (float units; 16B alignment holds throughout)
    float* a_src1 = ws;                        //  50,000
    float* a_dst1 = a_src1 + 50000;
    float* a_src2 = a_dst1 + 50000;
    float* a_dst2 = a_src2 + 50000;
    int*   cnt    = (int*)(a_dst2 + 50000);    //  50,000 (zeroed in phase 0)
    int*   srcs   = cnt + 50000;               //  50,000 * 64 ELL
    short* hbf1   = (short*)(srcs + 50000 * CAP);   // 6,400,000 bf16
    short* hbf2   = hbf1  + 6400000;           // 3,200,000 bf16
    short* Wf1    = hbf2  + 3200000;           //    32,768 bf16
    short* Wf2    = Wf1   + 32768;             //     8,192 bf16

    // ---- cooperative single-launch path ----
    int nb = 0;
    hipError_t err = hipOccupancyMaxActiveBlocksPerMultiprocessor(
        &nb, (const void*)gat_mega_kernel, 256, 0);
    bool coop = (err == hipSuccess && nb > 0);
    if (coop) {
        int G = nb * 256;                      // 256 CUs on MI355X
        if (G > RB3) G = RB3;
        void* args[] = {
            (void*)&x, (void*)&ei,
            (void*)&W1, (void*)&att_src1, (void*)&att_dst1, (void*)&b1,
            (void*)&W2, (void*)&att_src2, (void*)&att_dst2, (void*)&b2,
            (void*)&out,
            (void*)&cnt, (void*)&srcs, (void*)&hbf1, (void*)&hbf2,
            (void*)&Wf1, (void*)&Wf2,
            (void*)&a_src1, (void*)&a_dst1, (void*)&a_src2, (void*)&a_dst2};
        err = hipLaunchCooperativeKernel((const void*)gat_mega_kernel,
                                         dim3(G), dim3(256), args, 0, stream);
        if (err != hipSuccess) coop = false;
    }

    // ---- fallback: 4 regular launches ----
    if (!coop) {
        gat_init_kernel<<<196, 256, 0, stream>>>(cnt, W1, Wf1, W2, Wf2);
        gat_fat1_kernel<<<GB1 + EB1, 256, 0, stream>>>(
            x, Wf1, att_src1, att_dst1, hbf1, a_src1, a_dst1, ei, cnt, srcs);
        gat_aggr1_gemm2_kernel<<<AB2, 256, 0, stream>>>(
            cnt, srcs, a_src1, a_dst1, (const unsigned short*)hbf1, b1,
            Wf2, att_src2, att_dst2, hbf2, a_src2, a_dst2);
        gat_aggr2_kernel<<<RB3, 256, 0, stream>>>(
            cnt, srcs, a_src2, a_dst2, (const unsigned short*)hbf2, b2, out);
    }
}

// Round 11
// 252.576 us; speedup vs baseline: 2.4082x; 2.4082x over previous
//
#include <hip/hip_runtime.h>
#include <hip/hip_bf16.h>
#include <math.h>

#define N_NODES 50000
#define E_RAW   800000
#define E_TOT   850000
#define NEG_SLOPE 0.2f
#define CAP 64   // ELL slots per node; deg = Poisson(16)+1, P(>64) ~ 1e-13

typedef __attribute__((ext_vector_type(8))) short short8;
typedef __attribute__((ext_vector_type(4))) float f32x4;

__device__ __forceinline__ short f2bf(float f) {
    __hip_bfloat16 h = __float2bfloat16(f);
    return *reinterpret_cast<short*>(&h);
}
__device__ __forceinline__ unsigned int f2bfu(float f) {
    __hip_bfloat16 h = __float2bfloat16(f);
    return (unsigned int)*reinterpret_cast<unsigned short*>(&h);
}
__device__ __forceinline__ float bflo(unsigned int u) {
    return __uint_as_float(u << 16);
}
__device__ __forceinline__ float bfhi(unsigned int u) {
    return __uint_as_float(u & 0xffff0000u);
}

// ============ W -> B-fragment-order bf16 swizzle ============
template<int K, int N>
__device__ __forceinline__ void wf_body(
        int blk, const float* __restrict__ W, short* __restrict__ Wf) {
    constexpr int NT = N / 16;
    const int idx = blk * 256 + threadIdx.x;
    if (idx >= K * N) return;
    const int j  = idx & 7;
    const int n  = (idx >> 3) & 15;
    const int q  = (idx >> 7) & 3;
    const int t  = (idx >> 9) % NT;
    const int kc = idx / (512 * NT);
    const int k   = kc * 32 + q * 8 + j;
    const int col = t * 16 + n;
    Wf[idx] = f2bf(W[(size_t)k * N + col]);
}

// ===== init: zero cnt + both weight swizzles (196 blocks) =====
__global__ __launch_bounds__(256) void gat_init_kernel(
        int* __restrict__ cnt,
        const float* __restrict__ W1, short* __restrict__ Wf1,
        const float* __restrict__ W2, short* __restrict__ Wf2) {
    const int vb = blockIdx.x;
    const int idx = vb * 256 + threadIdx.x;
    if (idx < N_NODES) cnt[idx] = 0;
    if (vb < 128)      wf_body<256, 128>(vb, W1, Wf1);
    else if (vb < 160) wf_body<128, 64>(vb - 128, W2, Wf2);
}

// ============ MFMA GEMM + fused attention scores (device body) ============
template<int K, int N, bool BF16_IN>
__device__ __forceinline__ void gemm_att_body(
        const int blk,
        const float* __restrict__ xf, const short* __restrict__ xb,
        const short* __restrict__ Wf,
        const float* __restrict__ att_src, const float* __restrict__ att_dst,
        short* __restrict__ h_bf,
        float* __restrict__ a_src, float* __restrict__ a_dst) {
    constexpr int NT = N / 16;
    constexpr int KC = K / 32;
    const int tid  = threadIdx.x;
    const int lane = tid & 63;
    const int wv   = tid >> 6;
    const int mrow = lane & 15;
    const int q    = lane >> 4;

    const int row0 = blk * 64 + wv * 16;
    const int rowA = row0 + mrow;
    const int rowAc = rowA < N_NODES ? rowA : 0;

    f32x4 acc[NT];
    #pragma unroll
    for (int t = 0; t < NT; ++t) acc[t] = f32x4{0.f, 0.f, 0.f, 0.f};

    #pragma unroll
    for (int kc = 0; kc < KC; ++kc) {
        short8 a;
        if (BF16_IN) {
            a = *(const short8*)&xb[(size_t)rowAc * K + kc * 32 + q * 8];
        } else {
            const float4 f0 = *(const float4*)&xf[(size_t)rowAc * K + kc * 32 + q * 8];
            const float4 f1 = *(const float4*)&xf[(size_t)rowAc * K + kc * 32 + q * 8 + 4];
            a[0] = f2bf(f0.x); a[1] = f2bf(f0.y); a[2] = f2bf(f0.z); a[3] = f2bf(f0.w);
            a[4] = f2bf(f1.x); a[5] = f2bf(f1.y); a[6] = f2bf(f1.z); a[7] = f2bf(f1.w);
        }
        #pragma unroll
        for (int t = 0; t < NT; ++t) {
            const short8 b = *(const short8*)&Wf[((size_t)(kc * NT + t) * 64 + lane) * 8];
            acc[t] = __builtin_amdgcn_mfma_f32_16x16x32_bf16(a, b, acc[t], 0, 0, 0);
        }
    }

    // D layout: col = mrow, row = q*4 + r
    #pragma unroll
    for (int r = 0; r < 4; ++r) {
        const int rowD = row0 + q * 4 + r;
        float ps = 0.0f, pd = 0.0f;
        #pragma unroll
        for (int t = 0; t < NT; ++t) {
            const int col = t * 16 + mrow;
            ps = fmaf(acc[t][r], att_src[col], ps);
            pd = fmaf(acc[t][r], att_dst[col], pd);
        }
        #pragma unroll
        for (int off = 8; off > 0; off >>= 1) {
            ps += __shfl_xor(ps, off);
            pd += __shfl_xor(pd, off);
        }
        if (rowD < N_NODES) {
            if (mrow == 0) { a_src[rowD] = ps; a_dst[rowD] = pd; }
            #pragma unroll
            for (int t = 0; t < NT; ++t)
                h_bf[(size_t)rowD * N + t * 16 + mrow] = f2bf(acc[t][r]);
        }
    }
}

// ===== fat kernel: layer-1 GEMM (blocks [0,GB)) + ELL scatter (blocks [GB,..)) =====
template<int K, int N>
__global__ __launch_bounds__(256) void gat_fat1_kernel(
        const float* __restrict__ xf, const short* __restrict__ Wf,
        const float* __restrict__ att_src, const float* __restrict__ att_dst,
        short* __restrict__ h_bf,
        float* __restrict__ a_src, float* __restrict__ a_dst,
        const int* __restrict__ ei, int* __restrict__ cnt,
        int* __restrict__ srcs, int GB) {
    if ((int)blockIdx.x < GB) {
        gemm_att_body<K, N, false>(blockIdx.x, xf, nullptr, Wf,
                                   att_src, att_dst, h_bf, a_src, a_dst);
    } else {
        const int i = (blockIdx.x - GB) * 256 + threadIdx.x;
        if (i >= E_TOT) return;
        int s, d;
        if (i < E_RAW) { s = ei[i]; d = ei[E_RAW + i]; }
        else           { s = d = i - E_RAW; }
        const int c = atomicAdd(&cnt[d], 1);
        if (c < CAP) srcs[(d << 6) + c] = s;
    }
}

// ===== standalone GEMM (layer 2) =====
template<int K, int N, bool BF16_IN>
__global__ __launch_bounds__(256) void gat_gemm_att_kernel(
        const float* __restrict__ xf, const short* __restrict__ xb,
        const short* __restrict__ Wf,
        const float* __restrict__ att_src, const float* __restrict__ att_dst,
        short* __restrict__ h_bf,
        float* __restrict__ a_src, float* __restrict__ a_dst) {
    gemm_att_body<K, N, BF16_IN>(blockIdx.x, xf, xb, Wf,
                                 att_src, att_dst, h_bf, a_src, a_dst);
}

// ===== fused per-dst softmax + aggregation (ELL, one wave per dst) =====
// Phase A: lane j owns edge j; alpha in registers (deg <= CAP = 64).
// Phase B: 4 edges/iter; invalid slots clamp to edge 0 (L1-hot) with alpha=0.
template<int N, bool RELU, bool LSM, bool OUT_BF16>
__global__ __launch_bounds__(256) void gat_aggr_kernel(
        const int* __restrict__ cnt, const int* __restrict__ srcs,
        const float* __restrict__ a_src, const float* __restrict__ a_dst,
        const unsigned short* __restrict__ h_bf, const float* __restrict__ bias,
        float* __restrict__ outf, uint4* __restrict__ outb) {
    constexpr int EPL = N / 16;              // bf16 elems per lane (8 or 4)
    const int lane = threadIdx.x & 63;
    const int wave = threadIdx.x >> 6;
    const int d = blockIdx.x * 4 + wave;
    if (d >= N_NODES) return;
    const int beg = d << 6;                  // ELL base
    int deg = cnt[d];
    deg = deg < CAP ? deg : CAP;
    const float ad = a_dst[d];

    // ---- phase A: per-lane alpha ----
    const int sreg = srcs[beg + (lane < deg ? lane : 0)];
    float e;
    if (lane < deg) {
        float t = a_src[sreg] + ad;
        e = t > 0.0f ? t : NEG_SLOPE * t;
    } else {
        e = -1e30f;
    }
    float m = e;
    #pragma unroll
    for (int off = 32; off > 0; off >>= 1) m = fmaxf(m, __shfl_xor(m, off));
    const float anum = __expf(e - m);        // 0 for invalid lanes
    float ss = anum;
    #pragma unroll
    for (int off = 32; off > 0; off >>= 1) ss += __shfl_xor(ss, off);
    const float areg = anum / ss;            // lane j's alpha

    // ---- phase B: 4 rows per iteration ----
    const int g   = lane >> 4;
    const int sub = lane & 15;
    float acc[EPL];
    #pragma unroll
    for (int c = 0; c < EPL; ++c) acc[c] = 0.0f;

    for (int j = 0; j < deg; j += 4) {
        const int eidx = j + g;              // <= 63 always
        const int ec   = eidx < deg ? eidx : 0;   // clamp junk slots to edge 0
        const int s    = __shfl(sreg, ec);
        float alpha    = __shfl(areg, ec);
        if (eidx >= deg) alpha = 0.0f;
        const unsigned short* hp = h_bf + (size_t)s * N + sub * EPL;
        if (EPL == 8) {
            const uint4 hv = *(const uint4*)hp;
            acc[0] = fmaf(alpha, bflo(hv.x), acc[0]);
            acc[1] = fmaf(alpha, bfhi(hv.x), acc[1]);
            acc[2] = fmaf(alpha, bflo(hv.y), acc[2]);
            acc[3] = fmaf(alpha, bfhi(hv.y), acc[3]);
            acc[4] = fmaf(alpha, bflo(hv.z), acc[4]);
            acc[5] = fmaf(alpha, bfhi(hv.z), acc[5]);
            acc[6] = fmaf(alpha, bflo(hv.w), acc[6]);
            acc[7] = fmaf(alpha, bfhi(hv.w), acc[7]);
        } else {
            const uint2 hv = *(const uint2*)hp;
            acc[0] = fmaf(alpha, bflo(hv.x), acc[0]);
            acc[1] = fmaf(alpha, bfhi(hv.x), acc[1]);
            acc[2] = fmaf(alpha, bflo(hv.y), acc[2]);
            acc[3] = fmaf(alpha, bfhi(hv.y), acc[3]);
        }
    }

    // reduce the 4 edge-slots
    #pragma unroll
    for (int c = 0; c < EPL; ++c) {
        acc[c] += __shfl_xor(acc[c], 16);
        acc[c] += __shfl_xor(acc[c], 32);
    }

    // ---- epilogue ----
    if (LSM) {
        // N == 64: bias + log_softmax; lane sub holds cols sub*4..+3
        float v[4];
        #pragma unroll
        for (int c = 0; c < 4; ++c) v[c] = acc[c] + bias[sub * 4 + c];
        float mm = fmaxf(fmaxf(v[0], v[1]), fmaxf(v[2], v[3]));
        #pragma unroll
        for (int off = 1; off < 16; off <<= 1) mm = fmaxf(mm, __shfl_xor(mm, off));
        float es = __expf(v[0] - mm) + __expf(v[1] - mm)
                 + __expf(v[2] - mm) + __expf(v[3] - mm);
        #pragma unroll
        for (int off = 1; off < 16; off <<= 1) es += __shfl_xor(es, off);
        const float ls = logf(es);
        if (lane < 16) {
            float4 o;
            o.x = v[0] - mm - ls; o.y = v[1] - mm - ls;
            o.z = v[2] - mm - ls; o.w = v[3] - mm - ls;
            *(float4*)&outf[(size_t)d * N + sub * 4] = o;
        }
    } else {
        // N == 128: bias + relu, pack 8 bf16; lanes 0..15 write 16B each
        if (lane < 16) {
            const float4 b0 = *(const float4*)&bias[sub * 8];
            const float4 b1 = *(const float4*)&bias[sub * 8 + 4];
            float v[8];
            v[0] = acc[0] + b0.x; v[1] = acc[1] + b0.y;
            v[2] = acc[2] + b0.z; v[3] = acc[3] + b0.w;
            v[4] = acc[4] + b1.x; v[5] = acc[5] + b1.y;
            v[6] = acc[6] + b1.z; v[7] = acc[7] + b1.w;
            if (RELU)
                #pragma unroll
                for (int c = 0; c < 8; ++c) v[c] = fmaxf(v[c], 0.0f);
            uint4 p;
            p.x = f2bfu(v[0]) | (f2bfu(v[1]) << 16);
            p.y = f2bfu(v[2]) | (f2bfu(v[3]) << 16);
            p.z = f2bfu(v[4]) | (f2bfu(v[5]) << 16);
            p.w = f2bfu(v[6]) | (f2bfu(v[7]) << 16);
            outb[(size_t)d * 16 + sub] = p;
        }
    }
}

extern "C" void kernel_launch(void* const* d_in, const int* in_sizes, int n_in,
                              void* d_out, int out_size, void* d_ws, size_t ws_size,
                              hipStream_t stream) {
    const float* x        = (const float*)d_in[0];
    const int*   ei       = (const int*)  d_in[1];
    const float* W1       = (const float*)d_in[2];
    const float* att_src1 = (const float*)d_in[3];
    const float* att_dst1 = (const float*)d_in[4];
    const float* b1       = (const float*)d_in[5];
    const float* W2       = (const float*)d_in[6];
    const float* att_src2 = (const float*)d_in[7];
    const float* att_dst2 = (const float*)d_in[8];
    const float* b2       = (const float*)d_in[9];
    float* out = (float*)d_out;
    float* ws  = (float*)d_ws;

    // workspace layout (float units; 16B alignment holds throughout)
    float* a_src1 = ws;                        //  50,000
    float* a_dst1 = a_src1 + 50000;
    float* a_src2 = a_dst1 + 50000;
    float* a_dst2 = a_src2 + 50000;
    int*   cnt    = (int*)(a_dst2 + 50000);    //  50,000 (zeroed in init kernel)
    int*   srcs   = cnt + 50000;               //  50,000 * 64 ELL
    short* hbf1   = (short*)(srcs + 50000 * CAP);   // 6,400,000 bf16
    short* agg1b  = hbf1  + 6400000;           // 6,400,000 bf16
    short* Wf1    = agg1b + 6400000;           //    32,768 bf16
    short* Wf2    = Wf1   + 32768;             //     8,192 bf16
    short* hbf2   = hbf1;                      // alias: hbf1 dead after aggr1

    const int EB = (E_TOT + 255) / 256;        // 3321 scatter blocks
    const int GB = (N_NODES + 63) / 64;        // 782 gemm blocks

    // ---- init: zero cnt + weight swizzles (one kernel, no memset node) ----
    gat_init_kernel<<<196, 256, 0, stream>>>(cnt, W1, Wf1, W2, Wf2);

    // ---- layer-1 GEMM + ELL scatter, fused (gemm blocks first) ----
    gat_fat1_kernel<256, 128><<<GB + EB, 256, 0, stream>>>(
        x, Wf1, att_src1, att_dst1, hbf1, a_src1, a_dst1,
        ei, cnt, srcs, GB);

    // ---- layer-1 aggregation ----
    gat_aggr_kernel<128, true, false, true><<<12500, 256, 0, stream>>>(
        cnt, srcs, a_src1, a_dst1, (const unsigned short*)hbf1, b1,
        nullptr, (uint4*)agg1b);

    // ---- layer 2 ----
    gat_gemm_att_kernel<128, 64, true><<<GB, 256, 0, stream>>>(
        nullptr, agg1b, Wf2, att_src2, att_dst2, hbf2, a_src2, a_dst2);
    gat_aggr_kernel<64, false, true, false><<<12500, 256, 0, stream>>>(
        cnt, srcs, a_src2, a_dst2, (const unsigned short*)hbf2, b2,
        out, nullptr);
}